// Round 1
// baseline (4241.202 us; speedup 1.0000x reference)
//
#include <hip/hip_runtime.h>
#include <math.h>
#include <stdint.h>

// ReLSTM_18940805775611 — B=512, T=128, H=512, 2-layer LSTM, 128 TF + 127 AR.
// R19 (5051.8 us): 513 dispatches, KC=64, 2 barriers/iter, reg prefetch,
// (32 j, 8 m) grid for per-XCD weight L2 residency.
// R20 changes (overhead-bound theory: 32 barrier drains/dispatch at 1 wave/SIMD
// + ~510 launch gaps dominate; ideal compute is ~1.3 us/step-pair):
//  (1) KC 64->128 + true LDS double-buffer -> ONE __syncthreads per staging
//      iteration: layer1 barriers 32->8, layer0 16->4. Global prefetch issues
//      before the 16-MFMA block, ds_write lands after it (load latency hidden).
//  (2) Phase-1 layer fusion: layer0(t) chain is independent of layer1, so one
//      dispatch runs layer0(t) [z=0 blocks] + layer1(t-1) [z=1 blocks].
//      Phase-1 dispatches 256 -> 129; 512 blocks -> 2 blocks/CU -> 8 waves/CU
//      so the two layers' barrier stalls interleave. LDS 68KB/block fits 2/CU.
//  (3) Final barrier of the mma loop elided (no LDS reuse after).
// Same verified MFMA tiling/fragment maps and y0-from-c2 quirk as R17/R19.

namespace {
constexpr int NH  = 512;    // hidden
constexpr int NT  = 128;    // seq len
constexpr int NB  = 512;    // batch
constexpr int KC  = 128;    // k-chunk (bf16 elems)
constexpr int LDK = KC + 8; // LDS row stride: 272 B -> 16B-aligned rows, 2-way banks
}

typedef __attribute__((ext_vector_type(8))) short bf16x8;
typedef __attribute__((ext_vector_type(4))) float f32x4;

// Present in case the harness resolves this symbol.
__global__ void ReLSTM_18940805775611_kernel() {}

__device__ __forceinline__ unsigned short lstm9_f2b(float f) {
    union { float f; uint32_t i; } v; v.f = f;
    const uint32_t r = v.i + 0x7FFFu + ((v.i >> 16) & 1u);   // RNE
    return (unsigned short)(r >> 16);
}
__device__ __forceinline__ float lstm9_sig(float x) {
    return 1.0f / (1.0f + expf(-x));
}

// ---- sentinel: truncation diagnostic ----
__global__ void lstm9_mark(float* out) {
    const int i = blockIdx.x * blockDim.x + threadIdx.x;
    if (i < NB * NT) out[i] = 2.03125f;
}

// ---- one-time prep: weights fp32->bf16 (RNE), summed biases, zero states,
// ybuf := b_lin ----
__global__ void lstm9_prep(
    const float* whh0, const float* wih1, const float* whh1,
    const float* bih0, const float* bhh0, const float* bih1, const float* bhh1,
    const float* blin,
    unsigned short* wb0, unsigned short* wb1i, unsigned short* wb1h,
    float* bsum0, float* bsum1,
    unsigned short* hz, float* cz, float* ybuf)
{
    const size_t stride = (size_t)gridDim.x * blockDim.x;
    const size_t i0 = (size_t)blockIdx.x * blockDim.x + threadIdx.x;
    const size_t NW = (size_t)4 * NH * NH;
    for (size_t i = i0; i < NW; i += stride) {
        wb0 [i] = lstm9_f2b(whh0[i]);
        wb1i[i] = lstm9_f2b(wih1[i]);
        wb1h[i] = lstm9_f2b(whh1[i]);
    }
    for (size_t i = i0; i < (size_t)4 * NH; i += stride) {
        bsum0[i] = bih0[i] + bhh0[i];
        bsum1[i] = bih1[i] + bhh1[i];
    }
    for (size_t i = i0; i < (size_t)4 * NB * NH; i += stride) hz[i] = 0;
    for (size_t i = i0; i < (size_t)2 * NB * NH; i += stride) cz[i] = 0.0f;
    const float bl = blin[0];
    for (size_t i = i0; i < (size_t)NB * NT; i += stride) ybuf[i] = bl;
}

// ---- pipelined MFMA core: 64 batch rows x (16 j x 4 gates), K = NIT*KC.
// A/B sources switch from (A0,B0) to (A1,B1) at iteration 4 (each matrix is
// 512 K = 4 chunks). Double-buffered LDS, one barrier per iteration.
template<int NIT>
__device__ __forceinline__ void mma_core(
    unsigned short (*Ash)[64][LDK], unsigned short (*Bsh)[64][LDK],
    const unsigned short* __restrict__ A0, const unsigned short* __restrict__ A1,
    const unsigned short* __restrict__ B0, const unsigned short* __restrict__ B1,
    int tid,
    size_t gA0, size_t gA1, size_t gA2, size_t gA3,
    size_t gB0, size_t gB1, size_t gB2, size_t gB3,
    f32x4& a0, f32x4& a1, f32x4& a2, f32x4& a3)
{
    const int lane = tid & 63;
    const int wv   = tid >> 6;
    const int quad = lane >> 4;
    const int ln15 = lane & 15;
    const int ldr  = tid >> 4;        // 0..15: row within 16-row pass
    const int soff = (tid & 15) * 8;  // 16 segs x 8 bf16 = 128 = KC

    uint4 ra0 = *(const uint4*)(A0 + gA0);
    uint4 ra1 = *(const uint4*)(A0 + gA1);
    uint4 ra2 = *(const uint4*)(A0 + gA2);
    uint4 ra3 = *(const uint4*)(A0 + gA3);
    uint4 rb0 = *(const uint4*)(B0 + gB0);
    uint4 rb1 = *(const uint4*)(B0 + gB1);
    uint4 rb2 = *(const uint4*)(B0 + gB2);
    uint4 rb3 = *(const uint4*)(B0 + gB3);
    *(uint4*)&Ash[0][ldr     ][soff] = ra0;
    *(uint4*)&Ash[0][ldr + 16][soff] = ra1;
    *(uint4*)&Ash[0][ldr + 32][soff] = ra2;
    *(uint4*)&Ash[0][ldr + 48][soff] = ra3;
    *(uint4*)&Bsh[0][ldr     ][soff] = rb0;
    *(uint4*)&Bsh[0][ldr + 16][soff] = rb1;
    *(uint4*)&Bsh[0][ldr + 32][soff] = rb2;
    *(uint4*)&Bsh[0][ldr + 48][soff] = rb3;
    __syncthreads();

    #pragma unroll
    for (int it = 0; it < NIT; ++it) {
        const int cur = it & 1;
        if (it + 1 < NIT) {
            const int ni = it + 1;
            const unsigned short* ap = (ni < 4) ? A0 : A1;
            const unsigned short* bp = (ni < 4) ? B0 : B1;
            const size_t kc = (size_t)(ni & 3) * KC;
            ra0 = *(const uint4*)(ap + gA0 + kc);
            ra1 = *(const uint4*)(ap + gA1 + kc);
            ra2 = *(const uint4*)(ap + gA2 + kc);
            ra3 = *(const uint4*)(ap + gA3 + kc);
            rb0 = *(const uint4*)(bp + gB0 + kc);
            rb1 = *(const uint4*)(bp + gB1 + kc);
            rb2 = *(const uint4*)(bp + gB2 + kc);
            rb3 = *(const uint4*)(bp + gB3 + kc);
        }
        #pragma unroll
        for (int ks = 0; ks < KC; ks += 32) {
            const bf16x8 af = *(const bf16x8*)&Ash[cur][wv * 16 + ln15][ks + quad * 8];
            const bf16x8 b0 = *(const bf16x8*)&Bsh[cur][ln15][ks + quad * 8];
            const bf16x8 b1 = *(const bf16x8*)&Bsh[cur][16 + ln15][ks + quad * 8];
            const bf16x8 b2 = *(const bf16x8*)&Bsh[cur][32 + ln15][ks + quad * 8];
            const bf16x8 b3 = *(const bf16x8*)&Bsh[cur][48 + ln15][ks + quad * 8];
            a0 = __builtin_amdgcn_mfma_f32_16x16x32_bf16(af, b0, a0, 0, 0, 0);
            a1 = __builtin_amdgcn_mfma_f32_16x16x32_bf16(af, b1, a1, 0, 0, 0);
            a2 = __builtin_amdgcn_mfma_f32_16x16x32_bf16(af, b2, a2, 0, 0, 0);
            a3 = __builtin_amdgcn_mfma_f32_16x16x32_bf16(af, b3, a3, 0, 0, 0);
        }
        if (it + 1 < NIT) {
            const int nb = (it + 1) & 1;
            *(uint4*)&Ash[nb][ldr     ][soff] = ra0;
            *(uint4*)&Ash[nb][ldr + 16][soff] = ra1;
            *(uint4*)&Ash[nb][ldr + 32][soff] = ra2;
            *(uint4*)&Ash[nb][ldr + 48][soff] = ra3;
            *(uint4*)&Bsh[nb][ldr     ][soff] = rb0;
            *(uint4*)&Bsh[nb][ldr + 16][soff] = rb1;
            *(uint4*)&Bsh[nb][ldr + 32][soff] = rb2;
            *(uint4*)&Bsh[nb][ldr + 48][soff] = rb3;
            __syncthreads();   // buf[nb] published; buf[cur] free to overwrite next iter
        }
    }
}

// ---- layer-0 cell body: gates = x*w_ih0 + hPrev @ w_hh0^T + bsum0 ----
__device__ __forceinline__ void l0_body(
    unsigned short (*Ash)[64][LDK], unsigned short (*Bsh)[64][LDK],
    const float* __restrict__ xin, const float* __restrict__ ybuf,
    int col, int useY, int pubCol, float* __restrict__ outf,
    const unsigned short* __restrict__ hprev, unsigned short* __restrict__ hnext,
    float* __restrict__ c1,
    const unsigned short* __restrict__ wb0,
    const float* __restrict__ bsum0, const float* __restrict__ wih0f,
    int j0, int m0, int tid)
{
    const int lane = tid & 63;
    const int wv   = tid >> 6;
    const int quad = lane >> 4;
    const int ln15 = lane & 15;

    if (pubCol >= 0 && blockIdx.x == 0 && blockIdx.y == 0) {
        for (int r = tid; r < NB; r += 256)
            outf[(size_t)r * NT + pubCol] = ybuf[(size_t)r * NT + pubCol];
    }

    const int mb = m0 + wv * 16 + quad * 4;
    float xv[4];
    #pragma unroll
    for (int r = 0; r < 4; ++r)
        xv[r] = useY ? ybuf[(size_t)(mb + r) * NT + col]
                     : xin [(size_t)(mb + r) * NT + col];

    f32x4 a0 = {0.f, 0.f, 0.f, 0.f};
    f32x4 a1 = a0, a2 = a0, a3 = a0;
    const int ldr = tid >> 4;
    const int soff = (tid & 15) * 8;
    mma_core<4>(Ash, Bsh, hprev, hprev, wb0, wb0, tid,
        (size_t)(m0 + ldr) * NH + soff,
        (size_t)(m0 + ldr + 16) * NH + soff,
        (size_t)(m0 + ldr + 32) * NH + soff,
        (size_t)(m0 + ldr + 48) * NH + soff,
        (size_t)(0 * NH + j0 + ldr) * NH + soff,
        (size_t)(1 * NH + j0 + ldr) * NH + soff,
        (size_t)(2 * NH + j0 + ldr) * NH + soff,
        (size_t)(3 * NH + j0 + ldr) * NH + soff,
        a0, a1, a2, a3);

    const int jv = j0 + ln15;
    const float bi  = bsum0[jv],          bfv = bsum0[NH + jv];
    const float bg  = bsum0[2 * NH + jv], bo  = bsum0[3 * NH + jv];
    const float wxi = wih0f[jv],          wxf = wih0f[NH + jv];
    const float wxg = wih0f[2 * NH + jv], wxo = wih0f[3 * NH + jv];
    #pragma unroll
    for (int r = 0; r < 4; ++r) {
        const int m = mb + r;
        const float gi = a0[r] + fmaf(xv[r], wxi, bi);
        const float gf = a1[r] + fmaf(xv[r], wxf, bfv);
        const float gg = a2[r] + fmaf(xv[r], wxg, bg);
        const float go = a3[r] + fmaf(xv[r], wxo, bo);
        float cv = c1[(size_t)m * NH + jv];
        cv = lstm9_sig(gf) * cv + lstm9_sig(gi) * tanhf(gg);
        c1[(size_t)m * NH + jv] = cv;
        hnext[(size_t)m * NH + jv] = lstm9_f2b(lstm9_sig(go) * tanhf(cv));
    }
}

// ---- layer-1 cell body: gates = h1 @ w_ih1^T + h2 @ w_hh1^T + bsum1 ----
__device__ __forceinline__ void l1_body(
    unsigned short (*Ash)[64][LDK], unsigned short (*Bsh)[64][LDK],
    float (*redsh)[17],
    const unsigned short* __restrict__ h1cur, const unsigned short* __restrict__ h2prev,
    unsigned short* __restrict__ h2next, float* __restrict__ c2,
    const unsigned short* __restrict__ wb1i, const unsigned short* __restrict__ wb1h,
    const float* __restrict__ bsum1, const float* __restrict__ wlinf,
    float* __restrict__ ybuf, int ycol,
    int j0, int m0, int tid)
{
    const int lane = tid & 63;
    const int wv   = tid >> 6;
    const int quad = lane >> 4;
    const int ln15 = lane & 15;

    f32x4 a0 = {0.f, 0.f, 0.f, 0.f};
    f32x4 a1 = a0, a2 = a0, a3 = a0;
    const int ldr = tid >> 4;
    const int soff = (tid & 15) * 8;
    mma_core<8>(Ash, Bsh, h1cur, h2prev, wb1i, wb1h, tid,
        (size_t)(m0 + ldr) * NH + soff,
        (size_t)(m0 + ldr + 16) * NH + soff,
        (size_t)(m0 + ldr + 32) * NH + soff,
        (size_t)(m0 + ldr + 48) * NH + soff,
        (size_t)(0 * NH + j0 + ldr) * NH + soff,
        (size_t)(1 * NH + j0 + ldr) * NH + soff,
        (size_t)(2 * NH + j0 + ldr) * NH + soff,
        (size_t)(3 * NH + j0 + ldr) * NH + soff,
        a0, a1, a2, a3);

    const int jv = j0 + ln15;
    const float bi  = bsum1[jv],          bfv = bsum1[NH + jv];
    const float bg  = bsum1[2 * NH + jv], bo  = bsum1[3 * NH + jv];
    const int mb = m0 + wv * 16 + quad * 4;
    float hv[4];
    #pragma unroll
    for (int r = 0; r < 4; ++r) {
        const int m = mb + r;
        const float gi = a0[r] + bi;
        const float gf = a1[r] + bfv;
        const float gg = a2[r] + bg;
        const float go = a3[r] + bo;
        float cv = c2[(size_t)m * NH + jv];
        cv = lstm9_sig(gf) * cv + lstm9_sig(gi) * tanhf(gg);
        c2[(size_t)m * NH + jv] = cv;
        hv[r] = lstm9_sig(go) * tanhf(cv);
        h2next[(size_t)m * NH + jv] = lstm9_f2b(hv[r]);
    }

    if (ycol >= 0) {
        const float wl = wlinf[jv];
        #pragma unroll
        for (int r = 0; r < 4; ++r)
            redsh[wv * 16 + quad * 4 + r][ln15] = hv[r] * wl;
        __syncthreads();
        if (tid < 64) {
            float s = 0.0f;
            #pragma unroll
            for (int j = 0; j < 16; ++j) s += redsh[tid][j];
            atomicAdd(&ybuf[(size_t)(m0 + tid) * NT + ycol], s);
        }
    }
}

// ---- phase-2 kernels (serial AR chain: 2 dispatches/step is minimal) ----
__global__ __launch_bounds__(256) void lstm9_layer0(
    const float* __restrict__ xin, float* __restrict__ ybuf,
    int col, int useY, int pubCol, float* __restrict__ outf,
    const unsigned short* __restrict__ hprev, unsigned short* __restrict__ hnext,
    float* __restrict__ c1,
    const unsigned short* __restrict__ wb0,
    const float* __restrict__ bsum0, const float* __restrict__ wih0f)
{
    __shared__ unsigned short Ash[2][64][LDK];
    __shared__ unsigned short Bsh[2][64][LDK];
    l0_body(Ash, Bsh, xin, ybuf, col, useY, pubCol, outf, hprev, hnext, c1,
            wb0, bsum0, wih0f, blockIdx.x * 16, blockIdx.y * 64, threadIdx.x);
}

__global__ __launch_bounds__(256) void lstm9_layer1(
    const unsigned short* __restrict__ h1cur, const unsigned short* __restrict__ h2prev,
    unsigned short* __restrict__ h2next, float* __restrict__ c2,
    const unsigned short* __restrict__ wb1i, const unsigned short* __restrict__ wb1h,
    const float* __restrict__ bsum1, const float* __restrict__ wlinf,
    float* __restrict__ ybuf, int ycol)
{
    __shared__ unsigned short Ash[2][64][LDK];
    __shared__ unsigned short Bsh[2][64][LDK];
    __shared__ float redsh[64][17];
    l1_body(Ash, Bsh, redsh, h1cur, h2prev, h2next, c2, wb1i, wb1h, bsum1,
            wlinf, ybuf, ycol, blockIdx.x * 16, blockIdx.y * 64, threadIdx.x);
}

// ---- phase-1 fused kernel: z=0 -> layer0(t), z=1 -> layer1(t-1).
// layer0's recurrence is independent of layer1 in teacher-forced phase, so
// the two layers of consecutive steps run in one dispatch (2 blocks/CU).
__global__ __launch_bounds__(256, 2) void lstm9_fused1(
    const float* __restrict__ xin, int col, int doL0, int doL1,
    const unsigned short* __restrict__ h1rd, unsigned short* __restrict__ h1wr,
    float* __restrict__ c1,
    const unsigned short* __restrict__ wb0, const float* __restrict__ bsum0,
    const float* __restrict__ wih0f,
    const unsigned short* __restrict__ h2rd, unsigned short* __restrict__ h2wr,
    float* __restrict__ c2,
    const unsigned short* __restrict__ wb1i, const unsigned short* __restrict__ wb1h,
    const float* __restrict__ bsum1)
{
    __shared__ unsigned short Ash[2][64][LDK];
    __shared__ unsigned short Bsh[2][64][LDK];
    const int j0 = blockIdx.x * 16;
    const int m0 = blockIdx.y * 64;
    if (blockIdx.z == 0) {
        if (!doL0) return;
        l0_body(Ash, Bsh, xin, nullptr, col, 0, -1, nullptr,
                h1rd, h1wr, c1, wb0, bsum0, wih0f, j0, m0, threadIdx.x);
    } else {
        if (!doL1) return;
        l1_body(Ash, Bsh, nullptr, h1rd, h2rd, h2wr, c2, wb1i, wb1h, bsum1,
                nullptr, nullptr, -1, j0, m0, threadIdx.x);
    }
}

// ---- y0 head (reference quirk): y[:,0] = b_lin + c2 @ w_lin (CELL state!) ----
__global__ __launch_bounds__(256) void lstm9_head(
    const float* __restrict__ c2, const float* __restrict__ wlin,
    const float* __restrict__ blin, float* __restrict__ ybuf)
{
    __shared__ float acc[256];
    const int b   = blockIdx.x;
    const int tid = threadIdx.x;
    acc[tid] = c2[(size_t)b * NH + tid]       * wlin[tid]
             + c2[(size_t)b * NH + tid + 256] * wlin[tid + 256];
    __syncthreads();
    for (int off = 128; off > 0; off >>= 1) {
        if (tid < off) acc[tid] += acc[tid + off];
        __syncthreads();
    }
    if (tid == 0) ybuf[(size_t)b * NT] = blin[0] + acc[0];
}

// ---- final: all predictions to d_out as fp32 ----
__global__ void lstm9_emit(const float* __restrict__ ybuf, float* __restrict__ out) {
    const int i = blockIdx.x * blockDim.x + threadIdx.x;
    if (i < NB * NT) out[i] = ybuf[i];
}

extern "C" void kernel_launch(void* const* d_in, const int* in_sizes, int n_in,
                              void* d_out, int out_size, void* d_ws, size_t ws_size,
                              hipStream_t stream)
{
    int base = 3;
    if (!(n_in > 3 && in_sizes[3] == 4 * NH)) {
        for (int i = 1; i + 9 < n_in; ++i)
            if (in_sizes[i] == 4 * NH) { base = i; break; }
    }
    const float* xin  = (const float*)d_in[0];
    const float* wih0 = (const float*)d_in[base + 0];
    const float* whh0 = (const float*)d_in[base + 1];
    const float* bih0 = (const float*)d_in[base + 2];
    const float* bhh0 = (const float*)d_in[base + 3];
    const float* wih1 = (const float*)d_in[base + 4];
    const float* whh1 = (const float*)d_in[base + 5];
    const float* bih1 = (const float*)d_in[base + 6];
    const float* bhh1 = (const float*)d_in[base + 7];
    const float* wlin = (const float*)d_in[base + 8];
    const float* blin = (const float*)d_in[base + 9];
    float* outf = (float*)d_out;

    // ws layout (~10.3 MB): bf16 weights | bf16 h ping-pong | fp32 c, bias, y.
    const size_t NW = (size_t)4 * NH * NH;
    const size_t S  = (size_t)NB * NH;
    unsigned short* wb0  = (unsigned short*)d_ws;
    unsigned short* wb1i = wb0 + NW;
    unsigned short* wb1h = wb1i + NW;
    unsigned short* h1b0 = wb1h + NW;
    unsigned short* h1b1 = h1b0 + S;
    unsigned short* h2b0 = h1b1 + S;
    unsigned short* h2b1 = h2b0 + S;
    float* bsum0 = (float*)(h2b1 + S);
    float* bsum1 = bsum0 + 4 * NH;
    float* c1    = bsum1 + 4 * NH;
    float* c2    = c1 + S;
    float* ybuf  = c2 + S;
    unsigned short* h1p[2] = { h1b0, h1b1 };
    unsigned short* h2p[2] = { h2b0, h2b1 };

    lstm9_mark<<<(NB * NT + 255) / 256, 256, 0, stream>>>(outf);
    lstm9_prep<<<1024, 256, 0, stream>>>(whh0, wih1, whh1, bih0, bhh0, bih1, bhh1,
                                         blin, wb0, wb1i, wb1h, bsum0, bsum1,
                                         h1b0, c1, ybuf);

    dim3 grid(NH / 16, NB / 64);        // (32 j, 8 m): blk%8 spreads j over XCDs
    dim3 gridF(NH / 16, NB / 64, 2);    // fused: z=0 layer0, z=1 layer1

    // Phase 1 (teacher-forced), fused: dispatch t runs layer0(t) + layer1(t-1).
    // h1(t) -> h1p[(t+1)&1]; layer1 reads h1(t-1)=h1p[t&1], h2(t-2)=h2p[(t+1)&1],
    // writes h2(t-1) -> h2p[t&1]. After t=NT: h1(127) in h1p[0], h2(127) in h2p[0].
    for (int t = 0; t <= NT; ++t) {
        lstm9_fused1<<<gridF, 256, 0, stream>>>(
            xin, t, (t < NT) ? 1 : 0, (t >= 1) ? 1 : 0,
            h1p[t & 1], h1p[(t + 1) & 1], c1, wb0, bsum0, wih0,
            h2p[(t + 1) & 1], h2p[t & 1], c2, wb1i, wb1h, bsum1);
    }

    // Reference quirk: first prediction from the CELL state c2.
    lstm9_head<<<NB, 256, 0, stream>>>(c2, wlin, blin, ybuf);

    // Phase 2: autoregressive; layer0 consumes y[:,k-1] and publishes it.
    int p = 0;
    for (int k = 1; k < NT; ++k) {
        lstm9_layer0<<<grid, 256, 0, stream>>>(xin, ybuf, k - 1, 1, k - 1, outf,
                                               h1p[p], h1p[p ^ 1], c1,
                                               wb0, bsum0, wih0);
        lstm9_layer1<<<grid, 256, 0, stream>>>(h1p[p ^ 1], h2p[p], h2p[p ^ 1], c2,
                                               wb1i, wb1h, bsum1, wlin, ybuf, k);
        p ^= 1;
    }
    lstm9_emit<<<(NB * NT + 255) / 256, 256, 0, stream>>>(ybuf, outf);
}

// Round 2
// 4176.901 us; speedup vs baseline: 1.0154x; 1.0154x over previous
//
#include <hip/hip_runtime.h>
#include <math.h>
#include <stdint.h>

// ReLSTM_18940805775611 — B=512, T=128, H=512, 2-layer LSTM, 128 TF + 127 AR.
// R19: 5051.8us (513 dispatches). R20: 4241.2us (KC=128 dbuf + phase-1 layer
// fusion, ~388 dispatches) — still ~11us/dispatch vs ~1-2us of work: the
// serial-dispatch boundary (launch + ramp + L2 acquire/release) is the wall.
// R21: ONE persistent kernel for all 255 steps. Anti-R18 design (R18's
// grid.sync device-fence invalidated per-XCD L2s -> 7.8GB refetch -> 20ms):
//  - NO fences. Cross-block state (h1/h2 ping-pong, y-partials, flags) moves
//    via explicit sc0+sc1 (MALL-coherent) loads/stores only. Weights, biases,
//    c1/c2 (block-private) stay on the normal cached path -> per-XCD L2
//    resident for the whole run (bid%8 -> j-tile mapping, 768KB/XCD).
//  - Sync = per-m-group (32 blocks) flag barrier: producer bypass-stores data,
//    vmcnt(0), syncthreads, bypass-stores its flag slot; consumer wave0 polls
//    32 slots with one coalesced bypass load + __all, s_sleep throttled.
//    8 independent group pipelines; WAR on ping-pong buffers covered by
//    flagA(t-1)/flagA(t) ordering (per-block program order + barrier).
//  - Deadlock-safe: 256 blocks <= 256 CUs; LDS 74.2KB <= 80KB so even a
//    2-on-1-CU packing anomaly stays co-resident (launch_bounds(256,2)).
//  - y feedback + y0-from-c2 quirk via per-group partial dots (bypass),
//    redundantly summed by consumers — no atomics (no atomic-vs-bypass
//    visibility ambiguity).
// K-loop staging all in inline asm: A loads sc0 sc1, B loads normal, one
// register-tied s_waitcnt vmcnt(0) before the ds_writes (FIFO vmcnt semantics
// make any residual compiler waits over-wait, never under-wait).

namespace {
constexpr int NH  = 512;    // hidden
constexpr int NT  = 128;    // seq len
constexpr int NB  = 512;    // batch
constexpr int KC  = 128;    // k-chunk (bf16 elems)
constexpr int LDK = KC + 8; // LDS row stride
}

typedef __attribute__((ext_vector_type(8))) short bf16x8;
typedef __attribute__((ext_vector_type(4))) float f32x4;
typedef __attribute__((ext_vector_type(4))) unsigned int u32x4;

// Present in case the harness resolves this symbol.
__global__ void ReLSTM_18940805775611_kernel() {}

__device__ __forceinline__ unsigned short lstm9_f2b(float f) {
    union { float f; uint32_t i; } v; v.f = f;
    const uint32_t r = v.i + 0x7FFFu + ((v.i >> 16) & 1u);   // RNE
    return (unsigned short)(r >> 16);
}
__device__ __forceinline__ float lstm9_sig(float x) {
    return 1.0f / (1.0f + expf(-x));
}

// ---- sentinel: truncation diagnostic ----
__global__ void lstm9_mark(float* out) {
    const int i = blockIdx.x * blockDim.x + threadIdx.x;
    if (i < NB * NT) out[i] = 2.03125f;
}

// ---- one-time prep: weights fp32->bf16 (RNE), summed biases, zero states,
// zero flags ----
__global__ void lstm9_prep(
    const float* whh0, const float* wih1, const float* whh1,
    const float* bih0, const float* bhh0, const float* bih1, const float* bhh1,
    unsigned short* wb0, unsigned short* wb1i, unsigned short* wb1h,
    float* bsum0, float* bsum1,
    unsigned short* hz, float* cz, int* flags)
{
    const size_t stride = (size_t)gridDim.x * blockDim.x;
    const size_t i0 = (size_t)blockIdx.x * blockDim.x + threadIdx.x;
    const size_t NW = (size_t)4 * NH * NH;
    for (size_t i = i0; i < NW; i += stride) {
        wb0 [i] = lstm9_f2b(whh0[i]);
        wb1i[i] = lstm9_f2b(wih1[i]);
        wb1h[i] = lstm9_f2b(whh1[i]);
    }
    for (size_t i = i0; i < (size_t)4 * NH; i += stride) {
        bsum0[i] = bih0[i] + bhh0[i];
        bsum1[i] = bih1[i] + bhh1[i];
    }
    for (size_t i = i0; i < (size_t)4 * NB * NH; i += stride) hz[i] = 0;
    for (size_t i = i0; i < (size_t)2 * NB * NH; i += stride) cz[i] = 0.0f;
    for (size_t i = i0; i < (size_t)2 * 256 * 8 * 32; i += stride) flags[i] = 0;
}

// ---- asm memory helpers (sc0 sc1 = bypass L1+L2, coherent at MALL) ----
__device__ __forceinline__ void lstm9_ldA(u32x4& d, const unsigned short* p) {
    asm volatile("global_load_dwordx4 %0, %1, off sc0 sc1" : "=v"(d) : "v"(p));
}
__device__ __forceinline__ void lstm9_ldB(u32x4& d, const unsigned short* p) {
    asm volatile("global_load_dwordx4 %0, %1, off" : "=v"(d) : "v"(p));
}
__device__ __forceinline__ void lstm9_ldP(u32x4& d, const float* p) {
    asm volatile("global_load_dwordx4 %0, %1, off sc0 sc1" : "=v"(d) : "v"(p));
}
#define LSTM9_WAIT8(a,b,c,d,e,f,g,h) \
    asm volatile("s_waitcnt vmcnt(0)" \
        : "+v"(a),"+v"(b),"+v"(c),"+v"(d),"+v"(e),"+v"(f),"+v"(g),"+v"(h) :: "memory")
#define LSTM9_WAIT2(a,b) \
    asm volatile("s_waitcnt vmcnt(0)" : "+v"(a),"+v"(b) :: "memory")
__device__ __forceinline__ void lstm9_stH(unsigned short* p, unsigned short v) {
    unsigned int x = v;
    asm volatile("global_store_short %0, %1, off sc0 sc1" :: "v"(p), "v"(x) : "memory");
}
__device__ __forceinline__ void lstm9_stF(float* p, float v) {
    asm volatile("global_store_dword %0, %1, off sc0 sc1" :: "v"(p), "v"(v) : "memory");
}
__device__ __forceinline__ void lstm9_stI(int* p, int v) {
    asm volatile("global_store_dword %0, %1, off sc0 sc1" :: "v"(p), "v"(v) : "memory");
}
__device__ __forceinline__ void lstm9_drain() {
    asm volatile("s_waitcnt vmcnt(0)" ::: "memory");
}

// ---- group barrier: wait until all 32 flag slots of this group are set.
// wave0 polls (one coalesced bypass load across lanes), other waves park at
// the block barrier. Producers stored data + vmcnt(0) before their flag.
__device__ __forceinline__ void lstm9_waitgrp(const int* base) {
    if (threadIdx.x < 64) {
        const int sl = (int)threadIdx.x & 31;
        for (;;) {
            int f;
            asm volatile("global_load_dword %0, %1, off sc0 sc1\n\t"
                         "s_waitcnt vmcnt(0)"
                         : "=v"(f) : "v"(base + sl) : "memory");
            if (__all(f != 0)) break;
            __builtin_amdgcn_s_sleep(2);
        }
    }
    __syncthreads();
}

// ---- pipelined MFMA core: 64 batch rows x (16 j x 4 gates), K = NIT*KC.
// A via bypass loads (cross-block h state), B via normal loads (L2 weights).
// Source switch (A0,B0)->(A1,B1) at iteration 4. Double-buffered LDS,
// one barrier per iteration.
template<int NIT>
__device__ __forceinline__ void lstm9_mma(
    unsigned short (&Ash)[2][64][LDK], unsigned short (&Bsh)[2][64][LDK],
    const unsigned short* A0, const unsigned short* A1,
    const unsigned short* B0, const unsigned short* B1,
    size_t gA0, size_t gA1, size_t gA2, size_t gA3,
    size_t gB0, size_t gB1, size_t gB2, size_t gB3,
    f32x4& a0, f32x4& a1, f32x4& a2, f32x4& a3)
{
    const int tid  = threadIdx.x;
    const int lane = tid & 63;
    const int wv   = tid >> 6;
    const int quad = lane >> 4;
    const int ln15 = lane & 15;
    const int ldr  = tid >> 4;
    const int soff = (tid & 15) * 8;

    u32x4 ra0, ra1, ra2, ra3, rb0, rb1, rb2, rb3;
    lstm9_ldA(ra0, A0 + gA0);
    lstm9_ldA(ra1, A0 + gA1);
    lstm9_ldA(ra2, A0 + gA2);
    lstm9_ldA(ra3, A0 + gA3);
    lstm9_ldB(rb0, B0 + gB0);
    lstm9_ldB(rb1, B0 + gB1);
    lstm9_ldB(rb2, B0 + gB2);
    lstm9_ldB(rb3, B0 + gB3);
    LSTM9_WAIT8(ra0, ra1, ra2, ra3, rb0, rb1, rb2, rb3);
    *(u32x4*)&Ash[0][ldr     ][soff] = ra0;
    *(u32x4*)&Ash[0][ldr + 16][soff] = ra1;
    *(u32x4*)&Ash[0][ldr + 32][soff] = ra2;
    *(u32x4*)&Ash[0][ldr + 48][soff] = ra3;
    *(u32x4*)&Bsh[0][ldr     ][soff] = rb0;
    *(u32x4*)&Bsh[0][ldr + 16][soff] = rb1;
    *(u32x4*)&Bsh[0][ldr + 32][soff] = rb2;
    *(u32x4*)&Bsh[0][ldr + 48][soff] = rb3;
    __syncthreads();

    #pragma unroll
    for (int it = 0; it < NIT; ++it) {
        const int cur = it & 1;
        if (it + 1 < NIT) {
            const int ni = it + 1;
            const unsigned short* ap = (ni < 4) ? A0 : A1;
            const unsigned short* bp = (ni < 4) ? B0 : B1;
            const size_t kc = (size_t)(ni & 3) * KC;
            lstm9_ldA(ra0, ap + gA0 + kc);
            lstm9_ldA(ra1, ap + gA1 + kc);
            lstm9_ldA(ra2, ap + gA2 + kc);
            lstm9_ldA(ra3, ap + gA3 + kc);
            lstm9_ldB(rb0, bp + gB0 + kc);
            lstm9_ldB(rb1, bp + gB1 + kc);
            lstm9_ldB(rb2, bp + gB2 + kc);
            lstm9_ldB(rb3, bp + gB3 + kc);
        }
        #pragma unroll
        for (int ks = 0; ks < KC; ks += 32) {
            const bf16x8 af = *(const bf16x8*)&Ash[cur][wv * 16 + ln15][ks + quad * 8];
            const bf16x8 b0 = *(const bf16x8*)&Bsh[cur][ln15][ks + quad * 8];
            const bf16x8 b1 = *(const bf16x8*)&Bsh[cur][16 + ln15][ks + quad * 8];
            const bf16x8 b2 = *(const bf16x8*)&Bsh[cur][32 + ln15][ks + quad * 8];
            const bf16x8 b3 = *(const bf16x8*)&Bsh[cur][48 + ln15][ks + quad * 8];
            a0 = __builtin_amdgcn_mfma_f32_16x16x32_bf16(af, b0, a0, 0, 0, 0);
            a1 = __builtin_amdgcn_mfma_f32_16x16x32_bf16(af, b1, a1, 0, 0, 0);
            a2 = __builtin_amdgcn_mfma_f32_16x16x32_bf16(af, b2, a2, 0, 0, 0);
            a3 = __builtin_amdgcn_mfma_f32_16x16x32_bf16(af, b3, a3, 0, 0, 0);
        }
        if (it + 1 < NIT) {
            const int nb = (it + 1) & 1;
            LSTM9_WAIT8(ra0, ra1, ra2, ra3, rb0, rb1, rb2, rb3);
            *(u32x4*)&Ash[nb][ldr     ][soff] = ra0;
            *(u32x4*)&Ash[nb][ldr + 16][soff] = ra1;
            *(u32x4*)&Ash[nb][ldr + 32][soff] = ra2;
            *(u32x4*)&Ash[nb][ldr + 48][soff] = ra3;
            *(u32x4*)&Bsh[nb][ldr     ][soff] = rb0;
            *(u32x4*)&Bsh[nb][ldr + 16][soff] = rb1;
            *(u32x4*)&Bsh[nb][ldr + 32][soff] = rb2;
            *(u32x4*)&Bsh[nb][ldr + 48][soff] = rb3;
            __syncthreads();
        }
    }
}

// ---- the persistent kernel: all 255 steps (128 TF + 127 AR) ----
__global__ __launch_bounds__(256, 2) void lstm9_persist(
    const float* __restrict__ xin, float* __restrict__ outf,
    const unsigned short* __restrict__ wb0,
    const unsigned short* __restrict__ wb1i,
    const unsigned short* __restrict__ wb1h,
    const float* __restrict__ bsum0, const float* __restrict__ bsum1,
    const float* __restrict__ wih0f, const float* __restrict__ wlinf,
    const float* __restrict__ blinf,
    unsigned short* h1a, unsigned short* h1b,
    unsigned short* h2a, unsigned short* h2b,
    float* __restrict__ c1, float* __restrict__ c2,
    float* parts, int* flags)
{
    __shared__ unsigned short Ash[2][64][LDK];
    __shared__ unsigned short Bsh[2][64][LDK];
    __shared__ float redsh[64][17];
    __shared__ float ysh[64];

    const int tid  = threadIdx.x;
    const int lane = tid & 63;
    const int wv   = tid >> 6;
    const int quad = lane >> 4;
    const int ln15 = lane & 15;
    const int bid  = blockIdx.x;
    // bid%8 -> XCD (heuristic, perf only): j-tiles of one XCD are contiguous
    // so each XCD touches only 768KB of weights (L2-resident all run).
    const int jt = (bid & 7) * 4 + ((bid >> 3) & 3);  // j-tile 0..31
    const int g  = bid >> 5;                          // m-group 0..7
    const int j0 = jt * 16;
    const int m0 = g * 64;
    const int ldr  = tid >> 4;
    const int soff = (tid & 15) * 8;
    const int mb   = m0 + wv * 16 + quad * 4;
    const int jv   = j0 + ln15;

    const size_t gA0 = (size_t)(m0 + ldr)      * NH + soff;
    const size_t gA1 = (size_t)(m0 + ldr + 16) * NH + soff;
    const size_t gA2 = (size_t)(m0 + ldr + 32) * NH + soff;
    const size_t gA3 = (size_t)(m0 + ldr + 48) * NH + soff;
    const size_t gB0 = (size_t)(0 * NH + j0 + ldr) * NH + soff;
    const size_t gB1 = (size_t)(1 * NH + j0 + ldr) * NH + soff;
    const size_t gB2 = (size_t)(2 * NH + j0 + ldr) * NH + soff;
    const size_t gB3 = (size_t)(3 * NH + j0 + ldr) * NH + soff;

    // step-invariant scalars (registers for the whole run)
    const float b0i = bsum0[jv],          b0f = bsum0[NH + jv];
    const float b0g = bsum0[2 * NH + jv], b0o = bsum0[3 * NH + jv];
    const float wxi = wih0f[jv],          wxf = wih0f[NH + jv];
    const float wxg = wih0f[2 * NH + jv], wxo = wih0f[3 * NH + jv];
    const float b1i = bsum1[jv],          b1f = bsum1[NH + jv];
    const float b1g = bsum1[2 * NH + jv], b1o = bsum1[3 * NH + jv];
    const float wl  = wlinf[jv];
    const float bl  = blinf[0];

    unsigned short* h1p[2] = { h1a, h1b };
    unsigned short* h2p[2] = { h2a, h2b };
    int* flagA = flags;
    int* flagB = flags + 256 * 8 * 32;

    for (int t = 0; t < 256; ++t) {
        const unsigned short* h1rd = h1p[t & 1];
        unsigned short*       h1wr = h1p[(t + 1) & 1];
        const unsigned short* h2rd = h2p[t & 1];
        unsigned short*       h2wr = h2p[(t + 1) & 1];

        float xv[4];
        if (t < 128) {
            #pragma unroll
            for (int r = 0; r < 4; ++r)
                xv[r] = xin[(size_t)(mb + r) * NT + t];
        } else {
            // y(t-128) = bl + sum_j partials(t-1); partials covered by flagB(t-1)
            lstm9_waitgrp(flagB + ((t - 1) * 8 + g) * 32);
            const float* pslot = parts + (size_t)((t - 1) & 1) * NB * 32;
            const int row = tid >> 2, q = tid & 3;
            u32x4 v0, v1;
            lstm9_ldP(v0, pslot + (size_t)(m0 + row) * 32 + q * 8);
            lstm9_ldP(v1, pslot + (size_t)(m0 + row) * 32 + q * 8 + 4);
            LSTM9_WAIT2(v0, v1);
            const float* f0 = (const float*)&v0;
            const float* f1 = (const float*)&v1;
            float s = f0[0] + f0[1] + f0[2] + f0[3]
                    + f1[0] + f1[1] + f1[2] + f1[3];
            redsh[row][q] = s;
            __syncthreads();
            if (tid < 64) {
                const float y = bl + redsh[tid][0] + redsh[tid][1]
                                   + redsh[tid][2] + redsh[tid][3];
                ysh[tid] = y;
                if (jt == 0)
                    outf[(size_t)(m0 + tid) * NT + (t - 128)] = y;
            }
            __syncthreads();
            if (t == 255) break;   // last y published; done
            #pragma unroll
            for (int r = 0; r < 4; ++r)
                xv[r] = ysh[wv * 16 + quad * 4 + r];
        }

        // ---- layer 0: gates = x*w_ih0 + h1(t-1) @ w_hh0^T + bsum0 ----
        f32x4 a0 = {0.f, 0.f, 0.f, 0.f};
        f32x4 a1 = a0, a2 = a0, a3 = a0;
        lstm9_mma<4>(Ash, Bsh, h1rd, h1rd, wb0, wb0,
                     gA0, gA1, gA2, gA3, gB0, gB1, gB2, gB3, a0, a1, a2, a3);
        #pragma unroll
        for (int r = 0; r < 4; ++r) {
            const int m = mb + r;
            const float gi = a0[r] + fmaf(xv[r], wxi, b0i);
            const float gf = a1[r] + fmaf(xv[r], wxf, b0f);
            const float gg = a2[r] + fmaf(xv[r], wxg, b0g);
            const float go = a3[r] + fmaf(xv[r], wxo, b0o);
            float cv = c1[(size_t)m * NH + jv];            // block-private, cached
            cv = lstm9_sig(gf) * cv + lstm9_sig(gi) * tanhf(gg);
            c1[(size_t)m * NH + jv] = cv;
            lstm9_stH(h1wr + (size_t)m * NH + jv, lstm9_f2b(lstm9_sig(go) * tanhf(cv)));
        }
        lstm9_drain();
        __syncthreads();
        if (tid == 0) lstm9_stI(flagA + (t * 8 + g) * 32 + jt, 1);
        lstm9_waitgrp(flagA + (t * 8 + g) * 32);           // h1(t) all-j ready
        if (t >= 1 && t < 128)
            lstm9_waitgrp(flagB + ((t - 1) * 8 + g) * 32); // h2(t-1) ready (TF)

        // ---- layer 1: gates = h1(t) @ w_ih1^T + h2(t-1) @ w_hh1^T + bsum1 ----
        a0 = {0.f, 0.f, 0.f, 0.f}; a1 = a0; a2 = a0; a3 = a0;
        lstm9_mma<8>(Ash, Bsh, h1wr, h2rd, wb1i, wb1h,
                     gA0, gA1, gA2, gA3, gB0, gB1, gB2, gB3, a0, a1, a2, a3);
        float hv[4], cva[4];
        #pragma unroll
        for (int r = 0; r < 4; ++r) {
            const int m = mb + r;
            const float gi = a0[r] + b1i;
            const float gf = a1[r] + b1f;
            const float gg = a2[r] + b1g;
            const float go = a3[r] + b1o;
            float cv = c2[(size_t)m * NH + jv];            // block-private, cached
            cv = lstm9_sig(gf) * cv + lstm9_sig(gi) * tanhf(gg);
            c2[(size_t)m * NH + jv] = cv;
            cva[r] = cv;
            hv[r] = lstm9_sig(go) * tanhf(cv);
            lstm9_stH(h2wr + (size_t)m * NH + jv, lstm9_f2b(hv[r]));
        }
        if (t >= 127) {
            // partial dot for y(t-127): t==127 uses CELL state (reference quirk)
            #pragma unroll
            for (int r = 0; r < 4; ++r)
                redsh[wv * 16 + quad * 4 + r][ln15] = (t == 127 ? cva[r] : hv[r]) * wl;
            __syncthreads();
            if (tid < 64) {
                float s = 0.0f;
                #pragma unroll
                for (int j = 0; j < 16; ++j) s += redsh[tid][j];
                lstm9_stF(parts + (size_t)(t & 1) * NB * 32 + (size_t)(m0 + tid) * 32 + jt, s);
            }
        }
        lstm9_drain();
        __syncthreads();
        if (tid == 0) lstm9_stI(flagB + (t * 8 + g) * 32 + jt, 1);
    }
}

extern "C" void kernel_launch(void* const* d_in, const int* in_sizes, int n_in,
                              void* d_out, int out_size, void* d_ws, size_t ws_size,
                              hipStream_t stream)
{
    int base = 3;
    if (!(n_in > 3 && in_sizes[3] == 4 * NH)) {
        for (int i = 1; i + 9 < n_in; ++i)
            if (in_sizes[i] == 4 * NH) { base = i; break; }
    }
    const float* xin  = (const float*)d_in[0];
    const float* wih0 = (const float*)d_in[base + 0];
    const float* whh0 = (const float*)d_in[base + 1];
    const float* bih0 = (const float*)d_in[base + 2];
    const float* bhh0 = (const float*)d_in[base + 3];
    const float* wih1 = (const float*)d_in[base + 4];
    const float* whh1 = (const float*)d_in[base + 5];
    const float* bih1 = (const float*)d_in[base + 6];
    const float* bhh1 = (const float*)d_in[base + 7];
    const float* wlin = (const float*)d_in[base + 8];
    const float* blin = (const float*)d_in[base + 9];
    float* outf = (float*)d_out;

    // ws layout (~11.2 MB): bf16 weights | bf16 h ping-pong | fp32 bias, c,
    // y-partials | flags.
    const size_t NW = (size_t)4 * NH * NH;
    const size_t S  = (size_t)NB * NH;
    unsigned short* wb0  = (unsigned short*)d_ws;
    unsigned short* wb1i = wb0 + NW;
    unsigned short* wb1h = wb1i + NW;
    unsigned short* h1b0 = wb1h + NW;
    unsigned short* h1b1 = h1b0 + S;
    unsigned short* h2b0 = h1b1 + S;
    unsigned short* h2b1 = h2b0 + S;
    float* bsum0 = (float*)(h2b1 + S);
    float* bsum1 = bsum0 + 4 * NH;
    float* c1    = bsum1 + 4 * NH;
    float* c2    = c1 + S;
    float* parts = c2 + S;                  // 2 slots x 512 m x 32 j
    int*   flags = (int*)(parts + 2 * NB * 32);  // flagA | flagB

    lstm9_mark<<<(NB * NT + 255) / 256, 256, 0, stream>>>(outf);
    lstm9_prep<<<1024, 256, 0, stream>>>(whh0, wih1, whh1, bih0, bhh0, bih1, bhh1,
                                         wb0, wb1i, wb1h, bsum0, bsum1,
                                         h1b0, c1, flags);
    lstm9_persist<<<256, 256, 0, stream>>>(xin, outf, wb0, wb1i, wb1h,
                                           bsum0, bsum1, wih0, wlin, blin,
                                           h1b0, h1b1, h2b0, h2b1, c1, c2,
                                           parts, flags);
}